// Round 9
// baseline (687.936 us; speedup 1.0000x reference)
//
#include <hip/hip_runtime.h>
#include <hip/hip_bf16.h>

#define IN_DIM   128
#define HIDDEN   128
#define KDIM     256          // 2*IN_DIM
#define TILE_E   32           // edges per wave-tile
#define NTHREADS 512
#define LDBW     264          // sB row pitch in bf16 (528 B; conflict-free b128 pattern, 0 measured R4)

typedef __attribute__((ext_vector_type(8)))  short bf16x8;
typedef __attribute__((ext_vector_type(16))) float f32x16;

__device__ __forceinline__ unsigned short f2bf(float f) {
    union { __hip_bfloat16 h; unsigned short u; } cv;
    cv.h = __float2bfloat16(f);
    return cv.u;
}

// Fused prep: bf16 copies of both embedding tables + W1 transpose->bf16.
__global__ void prep_kernel(const float* __restrict__ pat,
                            const float* __restrict__ cond,
                            const float* __restrict__ W1,
                            unsigned short* __restrict__ pat_bf,
                            unsigned short* __restrict__ cond_bf,
                            unsigned short* __restrict__ W1T,
                            int n_vec, int do_tables) {
    const int w1_units = HIDDEN * KDIM / 8;         // 4096
    const long long total = do_tables ? (2LL * n_vec + w1_units) : w1_units;
    const long long stride = (long long)gridDim.x * blockDim.x;
    for (long long u = blockIdx.x * (long long)blockDim.x + threadIdx.x;
         u < total; u += stride) {
        if (do_tables && u < 2LL * n_vec) {
            int which = (u >= n_vec);
            long long v = which ? u - n_vec : u;
            const float* src = which ? cond : pat;
            unsigned short* dst = which ? cond_bf : pat_bf;
            long long base = v * 8;
            float4 x = *(const float4*)(src + base);
            float4 y = *(const float4*)(src + base + 4);
            unsigned short hv[8];
            hv[0]=f2bf(x.x); hv[1]=f2bf(x.y); hv[2]=f2bf(x.z); hv[3]=f2bf(x.w);
            hv[4]=f2bf(y.x); hv[5]=f2bf(y.y); hv[6]=f2bf(y.z); hv[7]=f2bf(y.w);
            *(uint4*)(dst + base) = *(uint4*)hv;
        } else {
            int idx = (int)(u - (do_tables ? 2LL * n_vec : 0));  // 0..4095
            int c  = idx >> 5;        // hidden col 0..127
            int k0 = (idx & 31) * 8;  // k offset
            unsigned short hv[8];
            #pragma unroll
            for (int j = 0; j < 8; ++j)
                hv[j] = f2bf(W1[(k0 + j) * HIDDEN + c]);
            *(uint4*)(W1T + c * KDIM + k0) = *(uint4*)hv;
        }
    }
}

// MFMA a 4-frag chunk Xa against B-frags from sB at K-steps ks0..ks0+3
#define MFMA_CHUNK(Xa, ks0)                                         \
    { _Pragma("unroll")                                             \
      for (int j = 0; j < 4; ++j) {                                 \
          const int ks = (ks0) + j;                                 \
          _Pragma("unroll")                                         \
          for (int nt = 0; nt < 4; ++nt) {                          \
              bf16x8 bfrag = *(const bf16x8*)                       \
                  &sB[(nt * 32 + c32) * LDBW + ks * 16 + hi * 8];   \
              acc[nt] = __builtin_amdgcn_mfma_f32_32x32x16_bf16(    \
                  Xa[j], bfrag, acc[nt], 0, 0, 0);                  \
          } } }

#define ISSUE_CHUNK(Xa, base, fo)                                   \
    { _Pragma("unroll")                                             \
      for (int j = 0; j < 4; ++j)                                   \
          Xa[j] = *(const bf16x8*)((base) + ((fo) + j) * 16); }

// Fast path: bf16 tables; ring-of-2 chunk pipeline; fold epilogue.
// __launch_bounds__(512,4): pin the 128-reg (VGPR+AGPR unified) budget that
// R4 proved spill-free. Total demand ~121: acc 64 + X ring 32 + misc ~25.
// Rounds 6-8 showed demand >128 ALWAYS spills (to scratch or LDS); the
// allocator never grants 256 regs here regardless of waves_per_eu hints.
__global__ __launch_bounds__(NTHREADS, 4)
void link_mlp_kernel(const unsigned short* __restrict__ tbl_p,
                     const unsigned short* __restrict__ tbl_c,
                     const int* __restrict__ eidx,
                     const unsigned short* __restrict__ W1T,
                     const float* __restrict__ b1,
                     const float* __restrict__ W2,
                     const float* __restrict__ b2,
                     float* __restrict__ out,
                     int E, int n_nodes, int ntiles)
{
    __shared__ unsigned short sB[HIDDEN * LDBW];   // W1T, padded pitch

    const int t = threadIdx.x;
    #pragma unroll
    for (int it = 0; it < 8; ++it) {
        int ci = it * NTHREADS + t;          // 0..4095
        int c = ci >> 5, j = ci & 31;
        *(uint4*)&sB[c * LDBW + j * 8] = *(const uint4*)(W1T + c * KDIM + j * 8);
    }
    __syncthreads();

    const int lane = t & 63;
    const int c32  = lane & 31;
    const int hi   = lane >> 5;

    float b1v[4], w2v[4];
    #pragma unroll
    for (int nt = 0; nt < 4; ++nt) {
        int col = nt * 32 + c32;
        b1v[nt] = b1[col];
        w2v[nt] = W2[col];
    }
    const float b2v = b2[0];

    const int wsl = gridDim.x * (NTHREADS / 64);
    int tile = blockIdx.x * (NTHREADS / 64) + (t >> 6);
    if (tile >= ntiles) return;

    bf16x8 X0[4], X1[4];    // ring: 2 chunks x 4 frags = 32 VGPR

    // ---- prologue: tile-0 indices; issue both patient chunks ----
    const unsigned short* bc;
    {
        int eC = min(tile * TILE_E + c32, E - 1);
        int np = eidx[eC];     np = min(max(np, 0), n_nodes - 1);
        int nc = eidx[E + eC]; nc = min(max(nc, 0), n_nodes - 1);
        const unsigned short* bp = tbl_p + np * IN_DIM + hi * 8;
        bc = tbl_c + nc * IN_DIM + hi * 8;
        ISSUE_CHUNK(X0, bp, 0);
        ISSUE_CHUNK(X1, bp, 4);
    }
    int npN = 0, ncN = 0;
    {
        int tn = tile + wsl;
        if (tn < ntiles) {
            int e2 = min(tn * TILE_E + c32, E - 1);
            npN = eidx[e2]; ncN = eidx[E + e2];
        }
    }

    while (true) {
        f32x16 acc[4];
        #pragma unroll
        for (int nt = 0; nt < 4; ++nt)
            acc[nt] = (f32x16){0.f,0.f,0.f,0.f,0.f,0.f,0.f,0.f,
                               0.f,0.f,0.f,0.f,0.f,0.f,0.f,0.f};

        // phase 1: consume patient-lo; issue cond-lo into freed X0
        MFMA_CHUNK(X0, 0);
        ISSUE_CHUNK(X0, bc, 0);
        // phase 2: consume patient-hi; issue cond-hi into freed X1
        MFMA_CHUNK(X1, 4);
        ISSUE_CHUNK(X1, bc, 4);

        // next-tile addresses from prefetched indices
        const int tn = tile + wsl;
        const unsigned short* bpN =
            tbl_p + min(max(npN, 0), n_nodes - 1) * IN_DIM + hi * 8;
        const unsigned short* bcN =
            tbl_c + min(max(ncN, 0), n_nodes - 1) * IN_DIM + hi * 8;

        // phase 3: consume cond-lo; issue next patient-lo
        MFMA_CHUNK(X0, 8);
        if (tn < ntiles) ISSUE_CHUNK(X0, bpN, 0);
        // phase 4: consume cond-hi; issue next patient-hi + idx two tiles out
        MFMA_CHUNK(X1, 12);
        if (tn < ntiles) {
            ISSUE_CHUNK(X1, bpN, 4);
            int tnn = min(tn + wsl, ntiles - 1);
            int e3 = min(tnn * TILE_E + c32, E - 1);
            npN = eidx[e3]; ncN = eidx[E + e3];
        }

        // ---- epilogue: relu + W2 dot, fold-reduce 16 vals over 32 lanes ----
        float v[16];
        #pragma unroll
        for (int r = 0; r < 16; ++r) {
            float s = 0.f;
            #pragma unroll
            for (int nt = 0; nt < 4; ++nt)
                s += fmaxf(acc[nt][r] + b1v[nt], 0.f) * w2v[nt];
            v[r] = s;
        }
        #pragma unroll
        for (int j = 0; j < 16; ++j) v[j] += __shfl_xor(v[j], 1, 64);
        const bool bb0 = (lane & 1);
        float w8[8];
        #pragma unroll
        for (int j = 0; j < 8; ++j) w8[j] = bb0 ? v[j + 8] : v[j];
        #pragma unroll
        for (int j = 0; j < 8; ++j) w8[j] += __shfl_xor(w8[j], 2, 64);
        const bool bb1 = (lane >> 1) & 1;
        float x4[4];
        #pragma unroll
        for (int j = 0; j < 4; ++j) x4[j] = bb1 ? w8[j + 4] : w8[j];
        #pragma unroll
        for (int j = 0; j < 4; ++j) x4[j] += __shfl_xor(x4[j], 4, 64);
        const bool bb2 = (lane >> 2) & 1;
        float y2[2];
        #pragma unroll
        for (int j = 0; j < 2; ++j) y2[j] = bb2 ? x4[j + 2] : x4[j];
        #pragma unroll
        for (int j = 0; j < 2; ++j) y2[j] += __shfl_xor(y2[j], 8, 64);
        const bool bb3 = (lane >> 3) & 1;
        float z = bb3 ? y2[1] : y2[0];
        z += __shfl_xor(z, 16, 64);

        {
            int r = ((lane & 1) << 3) | (((lane >> 1) & 1) << 2) |
                    (((lane >> 2) & 1) << 1) | ((lane >> 3) & 1);
            int row = (r & 3) + ((r >> 2) << 3) + 4 * hi;
            int erow = tile * TILE_E + row;
            if (!(lane & 16) && erow < E)
                out[erow] = 1.f / (1.f + __expf(-(z + b2v)));
        }

        if (tn >= ntiles) break;
        bc = bcN;
        tile = tn;
    }
}

// Fallback (ws too small for bf16 tables): R4 structure, f32 gather.
__global__ __launch_bounds__(NTHREADS, 4)
void link_mlp_f32_kernel(const float* __restrict__ pat,
                         const float* __restrict__ cond,
                         const int* __restrict__ eidx,
                         const unsigned short* __restrict__ W1T,
                         const float* __restrict__ b1,
                         const float* __restrict__ W2,
                         const float* __restrict__ b2,
                         float* __restrict__ out,
                         int E, int n_nodes, int ntiles)
{
    __shared__ unsigned short sB[HIDDEN * LDBW];
    __shared__ float sLog[8][TILE_E];

    const int t = threadIdx.x;
    #pragma unroll
    for (int it = 0; it < 8; ++it) {
        int ci = it * NTHREADS + t;
        int c = ci >> 5, j = ci & 31;
        *(uint4*)&sB[c * LDBW + j * 8] = *(const uint4*)(W1T + c * KDIM + j * 8);
    }
    __syncthreads();

    const int w    = t >> 6;
    const int lane = t & 63;
    const int c32  = lane & 31;
    const int hi   = lane >> 5;

    float b1v[4], w2v[4];
    #pragma unroll
    for (int nt = 0; nt < 4; ++nt) {
        int col = nt * 32 + c32;
        b1v[nt] = b1[col];
        w2v[nt] = W2[col];
    }
    const float b2v = b2[0];
    const int wslots = gridDim.x * (NTHREADS / 64);

    for (int tile = blockIdx.x * (NTHREADS / 64) + w; tile < ntiles; tile += wslots) {
        const int e  = tile * TILE_E + c32;
        const int eC = min(e, E - 1);
        int np = eidx[eC];     np = min(max(np, 0), n_nodes - 1);
        int nc = eidx[E + eC]; nc = min(max(nc, 0), n_nodes - 1);

        f32x16 acc[4];
        #pragma unroll
        for (int nt = 0; nt < 4; ++nt)
            acc[nt] = (f32x16){0.f,0.f,0.f,0.f,0.f,0.f,0.f,0.f,
                               0.f,0.f,0.f,0.f,0.f,0.f,0.f,0.f};

        const float* fp = pat  + (long long)np * IN_DIM + hi * 8;
        const float* fc = cond + (long long)nc * IN_DIM + hi * 8;
        #pragma unroll
        for (int ksb = 0; ksb < 4; ++ksb) {
            bf16x8 a[4];
            #pragma unroll
            for (int j = 0; j < 4; ++j) {
                int ks = ksb * 4 + j;
                const float* src = (ks < 8) ? (fp + ks * 16) : (fc + (ks - 8) * 16);
                float4 x = *(const float4*)src;
                float4 y = *(const float4*)(src + 4);
                unsigned short hv[8];
                hv[0]=f2bf(x.x); hv[1]=f2bf(x.y); hv[2]=f2bf(x.z); hv[3]=f2bf(x.w);
                hv[4]=f2bf(y.x); hv[5]=f2bf(y.y); hv[6]=f2bf(y.z); hv[7]=f2bf(y.w);
                a[j] = *(bf16x8*)hv;
            }
            #pragma unroll
            for (int j = 0; j < 4; ++j) {
                int ks = ksb * 4 + j;
                #pragma unroll
                for (int nt = 0; nt < 4; ++nt) {
                    bf16x8 b = *(const bf16x8*)
                        &sB[(nt * 32 + c32) * LDBW + ks * 16 + hi * 8];
                    acc[nt] = __builtin_amdgcn_mfma_f32_32x32x16_bf16(
                        a[j], b, acc[nt], 0, 0, 0);
                }
            }
        }

        float p[16];
        #pragma unroll
        for (int r = 0; r < 16; ++r) {
            float s = 0.f;
            #pragma unroll
            for (int nt = 0; nt < 4; ++nt)
                s += fmaxf(acc[nt][r] + b1v[nt], 0.f) * w2v[nt];
            p[r] = s;
        }
        #pragma unroll
        for (int off = 1; off < 32; off <<= 1)
            #pragma unroll
            for (int r = 0; r < 16; ++r)
                p[r] += __shfl_xor(p[r], off, 64);
        if (c32 == 0) {
            #pragma unroll
            for (int r = 0; r < 16; ++r)
                sLog[w][(r & 3) + 8 * (r >> 2) + 4 * hi] = p[r];
        }
        float x  = sLog[w][c32] + b2v;
        float sg = 1.f / (1.f + __expf(-x));
        if (hi == 0 && e < E) out[e] = sg;
    }
}

extern "C" void kernel_launch(void* const* d_in, const int* in_sizes, int n_in,
                              void* d_out, int out_size, void* d_ws, size_t ws_size,
                              hipStream_t stream) {
    const float* pat  = (const float*)d_in[0];
    const float* cond = (const float*)d_in[1];
    const int*   eidx = (const int*)d_in[2];     // int64 in reference -> int32 on device
    const float* W1   = (const float*)d_in[3];
    const float* b1   = (const float*)d_in[4];
    const float* W2   = (const float*)d_in[5];
    const float* b2   = (const float*)d_in[6];
    float*       out  = (float*)d_out;

    const int E       = in_sizes[2] / 2;
    const int n_nodes = in_sizes[0] / IN_DIM;
    const int ntiles  = (E + TILE_E - 1) / TILE_E;

    // ws layout: [0,64K) W1T bf16 | pat_bf | cond_bf
    unsigned short* W1T = (unsigned short*)d_ws;
    const size_t tbl_bytes = (size_t)n_nodes * IN_DIM * 2;
    unsigned short* pat_bf  = (unsigned short*)((char*)d_ws + 65536);
    unsigned short* cond_bf = (unsigned short*)((char*)d_ws + 65536 + tbl_bytes);
    const bool use_tbl = ws_size >= 65536 + 2 * tbl_bytes;

    const int n_vec = n_nodes * IN_DIM / 8;
    prep_kernel<<<2048, 256, 0, stream>>>(pat, cond, W1, pat_bf, cond_bf, W1T,
                                          n_vec, use_tbl ? 1 : 0);

    const int nblocks = 512;   // 2 blocks/CU, 16 waves/CU (R4-proven regime)
    if (use_tbl) {
        link_mlp_kernel<<<nblocks, NTHREADS, 0, stream>>>(
            pat_bf, cond_bf, eidx, W1T, b1, W2, b2, out, E, n_nodes, ntiles);
    } else {
        link_mlp_f32_kernel<<<nblocks, NTHREADS, 0, stream>>>(
            pat, cond, eidx, W1T, b1, W2, b2, out, E, n_nodes, ntiles);
    }
}

// Round 10
// 201.578 us; speedup vs baseline: 3.4128x; 3.4128x over previous
//
#include <hip/hip_runtime.h>
#include <hip/hip_bf16.h>

#define IN_DIM   128
#define HIDDEN   128
#define KDIM     256
#define NTH_G    512
#define LDBW     264          // padded W1T pitch in LDS (conflict-free, proven R4)
#define NSLICE   8
#define SLICE_D  16

typedef __attribute__((ext_vector_type(8)))  short bf16x8;
typedef __attribute__((ext_vector_type(16))) float f32x16;

__device__ __forceinline__ unsigned short f2bf(float f) {
    union { __hip_bfloat16 h; unsigned short u; } cv;
    cv.h = __float2bfloat16(f);
    return cv.u;
}
__device__ __forceinline__ float bf_lo(unsigned int v) { return __uint_as_float(v << 16); }
__device__ __forceinline__ float bf_hi(unsigned int v) { return __uint_as_float(v & 0xffff0000u); }

// K1: W1 [256][128] f32 -> W1T [128][256] bf16 (hidden-col rows, k-contiguous)
__global__ void w1t_kernel(const float* __restrict__ W1,
                           unsigned short* __restrict__ W1T) {
    int o = blockIdx.x * blockDim.x + threadIdx.x;      // 4096 vec8 units
    if (o >= HIDDEN * KDIM / 8) return;
    int c = o >> 5;            // hidden col 0..127
    int k0 = (o & 31) * 8;     // k offset
    unsigned short hv[8];
    #pragma unroll
    for (int j = 0; j < 8; ++j) hv[j] = f2bf(W1[(k0 + j) * HIDDEN + c]);
    *(uint4*)(W1T + c * KDIM + k0) = *(uint4*)hv;
}

// K2: per-node layer-1 projections, written SLICE-MAJOR bf16:
//   hp[slice][node][16] = (pat @ W1[:128] + b1) sliced ; hc = cond @ W1[128:]
// Structure = R4's verified MFMA tile minus the gather (A rows are consecutive).
__global__ __launch_bounds__(NTH_G, 4)
void hgemm_kernel(const float* __restrict__ pat,
                  const float* __restrict__ cond,
                  const unsigned short* __restrict__ W1T,
                  const float* __restrict__ b1,
                  unsigned short* __restrict__ hpS,
                  unsigned short* __restrict__ hcS,
                  int n_nodes)
{
    __shared__ unsigned short sB[HIDDEN * LDBW];
    const int t = threadIdx.x;
    #pragma unroll
    for (int it = 0; it < 8; ++it) {
        int ci = it * NTH_G + t;             // 0..4095
        int c = ci >> 5, j = ci & 31;
        *(uint4*)&sB[c * LDBW + j * 8] = *(const uint4*)(W1T + c * KDIM + j * 8);
    }
    __syncthreads();

    const int w = t >> 6, lane = t & 63, c32 = lane & 31, hi = lane >> 5;
    const int pass = w >> 2;                 // 0: hp(pat,W1a,+b1)  1: hc(cond,W1b)
    const int m    = w & 3;
    const int nb   = blockIdx.x * 128 + m * 32;
    if (nb >= n_nodes) return;               // after the only barrier — safe

    const float* tbl = pass ? cond : pat;
    const int row = min(nb + c32, n_nodes - 1);

    bf16x8 A[8];
    #pragma unroll
    for (int ks = 0; ks < 8; ++ks) {
        const float* ap = tbl + (long long)row * IN_DIM + ks * 16 + hi * 8;
        float4 x = *(const float4*)ap;
        float4 y = *(const float4*)(ap + 4);
        unsigned short hv[8];
        hv[0]=f2bf(x.x); hv[1]=f2bf(x.y); hv[2]=f2bf(x.z); hv[3]=f2bf(x.w);
        hv[4]=f2bf(y.x); hv[5]=f2bf(y.y); hv[6]=f2bf(y.z); hv[7]=f2bf(y.w);
        A[ks] = *(bf16x8*)hv;
    }

    f32x16 acc[4];
    #pragma unroll
    for (int nt = 0; nt < 4; ++nt)
        acc[nt] = (f32x16){0.f,0.f,0.f,0.f,0.f,0.f,0.f,0.f,
                           0.f,0.f,0.f,0.f,0.f,0.f,0.f,0.f};
    #pragma unroll
    for (int ks = 0; ks < 8; ++ks)
        #pragma unroll
        for (int nt = 0; nt < 4; ++nt) {
            bf16x8 b = *(const bf16x8*)
                &sB[(nt * 32 + c32) * LDBW + pass * 128 + ks * 16 + hi * 8];
            acc[nt] = __builtin_amdgcn_mfma_f32_32x32x16_bf16(A[ks], b, acc[nt], 0, 0, 0);
        }

    float b1v[4];
    #pragma unroll
    for (int nt = 0; nt < 4; ++nt) b1v[nt] = pass ? 0.f : b1[nt * 32 + c32];
    unsigned short* dst = pass ? hcS : hpS;

    #pragma unroll
    for (int nt = 0; nt < 4; ++nt) {
        int col = nt * 32 + c32;
        int sl = col >> 4, j = col & 15;
        unsigned short* dcol = dst + (long long)sl * n_nodes * SLICE_D + j;
        #pragma unroll
        for (int r = 0; r < 16; ++r) {
            int node = nb + (r & 3) + 8 * (r >> 2) + 4 * hi;   // verified C-layout
            if (node < n_nodes)
                dcol[(long long)node * SLICE_D] = f2bf(acc[nt][r] + b1v[nt]);
        }
    }
}

// K3: edge gather over ONE d-slice per block; slice = blockIdx&7 -> XCD-resident
// tables (2 x 1.6 MB per slice fits 4 MB per-XCD L2). Lane-per-edge; no LDS.
__global__ __launch_bounds__(256, 4)
void edge_kernel(const unsigned short* __restrict__ hpS,
                 const unsigned short* __restrict__ hcS,
                 const int* __restrict__ eidx,
                 const float* __restrict__ W2,
                 unsigned short* __restrict__ part,
                 int E, int n_nodes)
{
    const int slice = blockIdx.x & (NSLICE - 1);
    const int bid2  = blockIdx.x >> 3;
    const int lane  = threadIdx.x & 63;
    const int w     = threadIdx.x >> 6;

    float w2s[16];
    #pragma unroll
    for (int j = 0; j < 16; ++j) w2s[j] = W2[slice * SLICE_D + j];

    const unsigned short* hs = hpS + (long long)slice * n_nodes * SLICE_D;
    const unsigned short* hd = hcS + (long long)slice * n_nodes * SLICE_D;
    unsigned short* ps = part + (long long)slice * E;

    const int widS = bid2 * 4 + w;               // wave id within slice
    const int nwS  = (gridDim.x >> 3) * 4;       // waves per slice

    for (long long base = (long long)widS * 64; base < E; base += (long long)nwS * 64) {
        int e  = (int)base + lane;
        int eC = min(e, E - 1);
        int np = eidx[eC];     np = min(max(np, 0), n_nodes - 1);
        int nc = eidx[E + eC]; nc = min(max(nc, 0), n_nodes - 1);

        const uint4* sp = (const uint4*)(hs + (long long)np * SLICE_D);
        const uint4* dp = (const uint4*)(hd + (long long)nc * SLICE_D);
        uint4 s0 = sp[0], s1 = sp[1];
        uint4 d0 = dp[0], d1 = dp[1];

        unsigned int sa[8] = {s0.x, s0.y, s0.z, s0.w, s1.x, s1.y, s1.z, s1.w};
        unsigned int da[8] = {d0.x, d0.y, d0.z, d0.w, d1.x, d1.y, d1.z, d1.w};
        float p = 0.f;
        #pragma unroll
        for (int q = 0; q < 8; ++q) {
            float hlo = fmaxf(bf_lo(sa[q]) + bf_lo(da[q]), 0.f);
            float hhi = fmaxf(bf_hi(sa[q]) + bf_hi(da[q]), 0.f);
            p += hlo * w2s[2 * q] + hhi * w2s[2 * q + 1];
        }
        if (e < E) ps[e] = f2bf(p);
    }
}

// K4: sum 8 slice-partials, +b2, sigmoid, store f32.
__global__ __launch_bounds__(256)
void finalize_kernel(const unsigned short* __restrict__ part,
                     const float* __restrict__ b2,
                     float* __restrict__ out, int E)
{
    const float b2v = b2[0];
    const int stride = gridDim.x * blockDim.x;
    const int npair = (E + 1) >> 1;
    for (int i = blockIdx.x * blockDim.x + threadIdx.x; i < npair; i += stride) {
        int e0 = i * 2;
        float s0 = 0.f, s1 = 0.f;
        #pragma unroll
        for (int sl = 0; sl < NSLICE; ++sl) {
            const unsigned short* pp = part + (long long)sl * E + e0;
            s0 += __uint_as_float(((unsigned int)pp[0]) << 16);
            if (e0 + 1 < E) s1 += __uint_as_float(((unsigned int)pp[1]) << 16);
        }
        out[e0] = 1.f / (1.f + __expf(-(s0 + b2v)));
        if (e0 + 1 < E) out[e0 + 1] = 1.f / (1.f + __expf(-(s1 + b2v)));
    }
}

// Fallback (ws too small — not expected): R4-proven fused f32-gather kernel.
__global__ __launch_bounds__(NTH_G, 4)
void link_mlp_f32_kernel(const float* __restrict__ pat,
                         const float* __restrict__ cond,
                         const int* __restrict__ eidx,
                         const unsigned short* __restrict__ W1T,
                         const float* __restrict__ b1,
                         const float* __restrict__ W2,
                         const float* __restrict__ b2,
                         float* __restrict__ out,
                         int E, int n_nodes, int ntiles)
{
    __shared__ unsigned short sB[HIDDEN * LDBW];
    __shared__ float sLog[8][32];

    const int t = threadIdx.x;
    #pragma unroll
    for (int it = 0; it < 8; ++it) {
        int ci = it * NTH_G + t;
        int c = ci >> 5, j = ci & 31;
        *(uint4*)&sB[c * LDBW + j * 8] = *(const uint4*)(W1T + c * KDIM + j * 8);
    }
    __syncthreads();

    const int w = t >> 6, lane = t & 63, c32 = lane & 31, hi = lane >> 5;
    float b1v[4], w2v[4];
    #pragma unroll
    for (int nt = 0; nt < 4; ++nt) {
        int col = nt * 32 + c32;
        b1v[nt] = b1[col]; w2v[nt] = W2[col];
    }
    const float b2v = b2[0];
    const int wslots = gridDim.x * (NTH_G / 64);

    for (int tile = blockIdx.x * (NTH_G / 64) + w; tile < ntiles; tile += wslots) {
        const int e  = tile * 32 + c32;
        const int eC = min(e, E - 1);
        int np = eidx[eC];     np = min(max(np, 0), n_nodes - 1);
        int nc = eidx[E + eC]; nc = min(max(nc, 0), n_nodes - 1);

        f32x16 acc[4];
        #pragma unroll
        for (int nt = 0; nt < 4; ++nt)
            acc[nt] = (f32x16){0.f,0.f,0.f,0.f,0.f,0.f,0.f,0.f,
                               0.f,0.f,0.f,0.f,0.f,0.f,0.f,0.f};

        const float* fp = pat  + (long long)np * IN_DIM + hi * 8;
        const float* fc = cond + (long long)nc * IN_DIM + hi * 8;
        #pragma unroll
        for (int ksb = 0; ksb < 4; ++ksb) {
            bf16x8 a[4];
            #pragma unroll
            for (int j = 0; j < 4; ++j) {
                int ks = ksb * 4 + j;
                const float* src = (ks < 8) ? (fp + ks * 16) : (fc + (ks - 8) * 16);
                float4 x = *(const float4*)src;
                float4 y = *(const float4*)(src + 4);
                unsigned short hv[8];
                hv[0]=f2bf(x.x); hv[1]=f2bf(x.y); hv[2]=f2bf(x.z); hv[3]=f2bf(x.w);
                hv[4]=f2bf(y.x); hv[5]=f2bf(y.y); hv[6]=f2bf(y.z); hv[7]=f2bf(y.w);
                a[j] = *(bf16x8*)hv;
            }
            #pragma unroll
            for (int j = 0; j < 4; ++j) {
                int ks = ksb * 4 + j;
                #pragma unroll
                for (int nt = 0; nt < 4; ++nt) {
                    bf16x8 b = *(const bf16x8*)
                        &sB[(nt * 32 + c32) * LDBW + ks * 16 + hi * 8];
                    acc[nt] = __builtin_amdgcn_mfma_f32_32x32x16_bf16(a[j], b, acc[nt], 0, 0, 0);
                }
            }
        }

        float p[16];
        #pragma unroll
        for (int r = 0; r < 16; ++r) {
            float s = 0.f;
            #pragma unroll
            for (int nt = 0; nt < 4; ++nt)
                s += fmaxf(acc[nt][r] + b1v[nt], 0.f) * w2v[nt];
            p[r] = s;
        }
        #pragma unroll
        for (int off = 1; off < 32; off <<= 1)
            #pragma unroll
            for (int r = 0; r < 16; ++r)
                p[r] += __shfl_xor(p[r], off, 64);
        if (c32 == 0) {
            #pragma unroll
            for (int r = 0; r < 16; ++r)
                sLog[w][(r & 3) + 8 * (r >> 2) + 4 * hi] = p[r];
        }
        float x  = sLog[w][c32] + b2v;
        float sg = 1.f / (1.f + __expf(-x));
        if (hi == 0 && e < E) out[e] = sg;
    }
}

extern "C" void kernel_launch(void* const* d_in, const int* in_sizes, int n_in,
                              void* d_out, int out_size, void* d_ws, size_t ws_size,
                              hipStream_t stream) {
    const float* pat  = (const float*)d_in[0];
    const float* cond = (const float*)d_in[1];
    const int*   eidx = (const int*)d_in[2];     // int64 in reference -> int32 on device
    const float* W1   = (const float*)d_in[3];
    const float* b1   = (const float*)d_in[4];
    const float* W2   = (const float*)d_in[5];
    const float* b2   = (const float*)d_in[6];
    float*       out  = (float*)d_out;

    const int E       = in_sizes[2] / 2;
    const int n_nodes = in_sizes[0] / IN_DIM;

    // ws layout: W1T 64KB | hpS (slice-major bf16) | hcS | part [8][E] bf16
    unsigned short* W1T = (unsigned short*)d_ws;
    const size_t tblB  = (size_t)n_nodes * HIDDEN * 2;
    const size_t partB = (size_t)NSLICE * E * 2;
    unsigned short* hpS  = (unsigned short*)((char*)d_ws + 65536);
    unsigned short* hcS  = (unsigned short*)((char*)d_ws + 65536 + tblB);
    unsigned short* prt  = (unsigned short*)((char*)d_ws + 65536 + 2 * tblB);
    const bool use_new = ws_size >= 65536 + 2 * tblB + partB;

    w1t_kernel<<<16, 256, 0, stream>>>(W1, W1T);

    if (use_new) {
        hgemm_kernel<<<(n_nodes + 127) / 128, NTH_G, 0, stream>>>(
            pat, cond, W1T, b1, hpS, hcS, n_nodes);
        edge_kernel<<<2048, 256, 0, stream>>>(hpS, hcS, eidx, W2, prt, E, n_nodes);
        finalize_kernel<<<1024, 256, 0, stream>>>(prt, b2, out, E);
    } else {
        const int ntiles = (E + 31) / 32;
        link_mlp_f32_kernel<<<512, NTH_G, 0, stream>>>(
            pat, cond, eidx, W1T, b1, W2, b2, out, E, n_nodes, ntiles);
    }
}